// Round 1
// baseline (157.846 us; speedup 1.0000x reference)
//
#include <hip/hip_runtime.h>
#include <stdint.h>

#define NUM_ACT 6
#define NUM_OPP 3
#define NUM_SAMPLE 80
#define BATCH 4096
#define DIM 512

// ---------------- JAX threefry2x32 (key = (0, 42)) ----------------
__device__ __forceinline__ uint32_t rotl32(uint32_t x, int d) {
  return (x << d) | (x >> (32 - d));
}

__device__ __forceinline__ void tf_round4(uint32_t& x0, uint32_t& x1,
                                          int r0, int r1, int r2, int r3) {
  x0 += x1; x1 = rotl32(x1, r0); x1 ^= x0;
  x0 += x1; x1 = rotl32(x1, r1); x1 ^= x0;
  x0 += x1; x1 = rotl32(x1, r2); x1 ^= x0;
  x0 += x1; x1 = rotl32(x1, r3); x1 ^= x0;
}

__device__ __forceinline__ void threefry2x32(uint32_t k0, uint32_t k1,
                                             uint32_t& x0, uint32_t& x1) {
  const uint32_t ks2 = k0 ^ k1 ^ 0x1BD11BDAu;
  x0 += k0;  x1 += k1;
  tf_round4(x0, x1, 13, 15, 26, 6);  x0 += k1;  x1 += ks2 + 1u;
  tf_round4(x0, x1, 17, 29, 16, 24); x0 += ks2; x1 += k0  + 2u;
  tf_round4(x0, x1, 13, 15, 26, 6);  x0 += k0;  x1 += k1  + 3u;
  tf_round4(x0, x1, 17, 29, 16, 24); x0 += k1;  x1 += ks2 + 4u;
  tf_round4(x0, x1, 13, 15, 26, 6);  x0 += ks2; x1 += k0  + 5u;
}

// jax_threefry_partitionable=True path: counter = 64-bit flat index (hi=0),
// 32-bit bits = out0 ^ out1.
__device__ __forceinline__ float jax_gumbel(uint32_t flat_idx) {
  uint32_t x0 = 0u, x1 = flat_idx;
  threefry2x32(0u, 42u, x0, x1);
  uint32_t bits = x0 ^ x1;
  uint32_t fb = (bits >> 9) | 0x3f800000u;
  float f = __uint_as_float(fb) - 1.0f;          // [0,1)
  float u = fmaxf(f, 1.17549435e-38f);           // uniform(tiny, 1)
  return -logf(-logf(u));
}

// ---------------- K1: logits[3,B,6] (+b_opp) and xW[B,6] ----------------
// thread per (b, c), c in [0,24): c<18 -> opponent col (k=c/6, a=c%6), else agent col a=c-18
__global__ __launch_bounds__(256) void k1_gemm(
    const float* __restrict__ x, const float* __restrict__ Wopp,
    const float* __restrict__ bopp, const float* __restrict__ W,
    float* __restrict__ ws_logits, float* __restrict__ ws_xw) {
  int tid = blockIdx.x * 256 + threadIdx.x;     // 98304 total
  int b = tid / 24;
  int c = tid - b * 24;
  const float* xrow = x + b * DIM;
  const float* wcol;
  if (c < 18) wcol = Wopp + (c / 6) * (DIM * NUM_ACT) + (c % 6);
  else        wcol = W + (c - 18);
  float a0 = 0.f, a1 = 0.f, a2 = 0.f, a3 = 0.f;
  for (int d = 0; d < DIM; d += 4) {
    float4 xv = *(const float4*)(xrow + d);
    a0 = fmaf(xv.x, wcol[(d + 0) * 6], a0);
    a1 = fmaf(xv.y, wcol[(d + 1) * 6], a1);
    a2 = fmaf(xv.z, wcol[(d + 2) * 6], a2);
    a3 = fmaf(xv.w, wcol[(d + 3) * 6], a3);
  }
  float r = (a0 + a1) + (a2 + a3);
  if (c < 18) {
    r += bopp[c];                               // b_opp[k][a] == bopp[c]
    int k = c / 6, a = c - k * 6;
    ws_logits[(k * BATCH + b) * NUM_ACT + a] = r;
  } else {
    ws_xw[b * NUM_ACT + (c - 18)] = r;
  }
}

// ---------------- K2: softmax rows -> dist (d_out) + entropy partial ----------------
__global__ __launch_bounds__(256) void k2_softmax(
    const float* __restrict__ ws_logits, float* __restrict__ dout,
    float* __restrict__ ws_ent) {
  int row = blockIdx.x * 256 + threadIdx.x;     // 12288 rows exactly
  float l[NUM_ACT];
#pragma unroll
  for (int a = 0; a < NUM_ACT; a++) l[a] = ws_logits[row * NUM_ACT + a];
  float m = l[0];
#pragma unroll
  for (int a = 1; a < NUM_ACT; a++) m = fmaxf(m, l[a]);
  float e[NUM_ACT], Z = 0.f;
#pragma unroll
  for (int a = 0; a < NUM_ACT; a++) { e[a] = expf(l[a] - m); Z += e[a]; }
  float logZ = logf(Z);
  float H = 0.f;
#pragma unroll
  for (int a = 0; a < NUM_ACT; a++) {
    float pa = e[a] / Z;
    dout[BATCH * NUM_ACT + row * NUM_ACT + a] = pa;
    H -= pa * ((l[a] - m) - logZ);
  }
  // wave-level reduce then one atomic per wave
#pragma unroll
  for (int off = 32; off > 0; off >>= 1) H += __shfl_down(H, off);
  if ((threadIdx.x & 63) == 0) atomicAdd(ws_ent, H);
}

// ---------------- K3: sample + p2 + agent softmax + output ----------------
__global__ __launch_bounds__(256) void k3_agent(
    const float* __restrict__ ws_logits, const float* __restrict__ ws_xw,
    const float* __restrict__ W, const float* __restrict__ bias,
    const float* __restrict__ ws_ent, float* __restrict__ dout) {
  int b = blockIdx.x;
  int t = threadIdx.x;
  __shared__ float s_logits[NUM_OPP][NUM_ACT];
  __shared__ float s_dist[NUM_OPP][NUM_ACT];
  __shared__ float s_xw[NUM_ACT];
  __shared__ float s_bias[NUM_ACT];
  __shared__ float s_W2[NUM_OPP * NUM_ACT][NUM_ACT];   // W rows 512..529
  __shared__ int   s_act[NUM_OPP][NUM_SAMPLE];
  __shared__ float s_prob[NUM_OPP][NUM_SAMPLE];
  __shared__ float s_p1[NUM_SAMPLE];
  __shared__ float s_sum;
  __shared__ float s_wq[NUM_SAMPLE][NUM_ACT];

  if (t < 18) {
    int k = t / 6, a = t - k * 6;
    s_logits[k][a] = ws_logits[(k * BATCH + b) * NUM_ACT + a];
    s_dist[k][a]   = dout[BATCH * NUM_ACT + (k * BATCH + b) * NUM_ACT + a];
  }
  if (t < NUM_ACT) { s_xw[t] = ws_xw[b * NUM_ACT + t]; s_bias[t] = bias[t]; }
  if (t >= 32 && t < 32 + 108) {
    int i = t - 32;
    s_W2[i / 6][i % 6] = W[DIM * NUM_ACT + i];
  }
  __syncthreads();

  if (t < NUM_OPP * NUM_SAMPLE) {
    int k = t / NUM_SAMPLE, s = t - k * NUM_SAMPLE;
    uint32_t base = ((uint32_t)(k * NUM_SAMPLE + s) * BATCH + (uint32_t)b) * NUM_ACT;
    float best = -3.4e38f;
    int bestA = 0;
#pragma unroll
    for (int a = 0; a < NUM_ACT; a++) {
      float v = s_logits[k][a] + jax_gumbel(base + a);
      if (v > best) { best = v; bestA = a; }   // first max wins (strict >)
    }
    s_act[k][s] = bestA;
    s_prob[k][s] = s_dist[k][bestA];
  }
  __syncthreads();

  if (t < NUM_SAMPLE) s_p1[t] = s_prob[0][t] * s_prob[1][t] * s_prob[2][t];
  __syncthreads();
  if (t == 0) {
    float sm = 0.f;
    for (int s = 0; s < NUM_SAMPLE; s++) sm += s_p1[s];
    s_sum = sm;
  }
  __syncthreads();

  if (t < NUM_SAMPLE) {
    float w = s_p1[t] / s_sum;
    int a0 = s_act[0][t], a1 = s_act[1][t], a2 = s_act[2][t];
    float la[NUM_ACT];
#pragma unroll
    for (int a = 0; a < NUM_ACT; a++)
      la[a] = s_xw[a] + s_W2[a0][a] + s_W2[6 + a1][a] + s_W2[12 + a2][a] + s_bias[a];
    float m = la[0];
#pragma unroll
    for (int a = 1; a < NUM_ACT; a++) m = fmaxf(m, la[a]);
    float e[NUM_ACT], Z = 0.f;
#pragma unroll
    for (int a = 0; a < NUM_ACT; a++) { e[a] = expf(la[a] - m); Z += e[a]; }
#pragma unroll
    for (int a = 0; a < NUM_ACT; a++) s_wq[t][a] = w * (e[a] / Z);
  }
  __syncthreads();

  if (t < NUM_ACT) {
    float sm = 0.f;
    for (int s = 0; s < NUM_SAMPLE; s++) sm += s_wq[s][t];
    dout[b * NUM_ACT + t] = sm;
  }
  if (b == 0 && t == 255) {
    // entropy = global sum / (3*4096); ws_ent complete after K2 (stream order)
    dout[BATCH * NUM_ACT + NUM_OPP * BATCH * NUM_ACT] = ws_ent[0] * (1.0f / 12288.0f);
  }
}

extern "C" void kernel_launch(void* const* d_in, const int* in_sizes, int n_in,
                              void* d_out, int out_size, void* d_ws, size_t ws_size,
                              hipStream_t stream) {
  const float* x    = (const float*)d_in[0];
  const float* Wopp = (const float*)d_in[1];
  const float* bopp = (const float*)d_in[2];
  const float* W    = (const float*)d_in[3];
  const float* bias = (const float*)d_in[4];
  float* out = (float*)d_out;
  float* ws  = (float*)d_ws;
  float* ws_logits = ws;                 // 3*4096*6 = 73728 floats
  float* ws_xw     = ws + 73728;         // 4096*6  = 24576 floats
  float* ws_ent    = ws + 98304;         // 1 float accumulator

  hipMemsetAsync(ws_ent, 0, sizeof(float), stream);
  k1_gemm<<<384, 256, 0, stream>>>(x, Wopp, bopp, W, ws_logits, ws_xw);
  k2_softmax<<<48, 256, 0, stream>>>(ws_logits, out, ws_ent);
  k3_agent<<<4096, 256, 0, stream>>>(ws_logits, ws_xw, W, bias, ws_ent, out);
}

// Round 2
// 107.250 us; speedup vs baseline: 1.4718x; 1.4718x over previous
//
#include <hip/hip_runtime.h>
#include <stdint.h>

#define NUM_ACT 6
#define NUM_OPP 3
#define NUM_SAMPLE 80
#define BATCH 4096
#define DIM 512
#define ACC_STRIDE 98304   /* BATCH*24 */
#define TROWS 32
#define LDSPAD 132         /* 128 + 4: breaks 512B bank alias, keeps 16B align */

// ---------------- JAX threefry2x32 (key = (0, 42)) ----------------
__device__ __forceinline__ uint32_t rotl32(uint32_t x, int d) {
  return (x << d) | (x >> (32 - d));
}

__device__ __forceinline__ void tf_round4(uint32_t& x0, uint32_t& x1,
                                          int r0, int r1, int r2, int r3) {
  x0 += x1; x1 = rotl32(x1, r0); x1 ^= x0;
  x0 += x1; x1 = rotl32(x1, r1); x1 ^= x0;
  x0 += x1; x1 = rotl32(x1, r2); x1 ^= x0;
  x0 += x1; x1 = rotl32(x1, r3); x1 ^= x0;
}

__device__ __forceinline__ void threefry2x32(uint32_t k0, uint32_t k1,
                                             uint32_t& x0, uint32_t& x1) {
  const uint32_t ks2 = k0 ^ k1 ^ 0x1BD11BDAu;
  x0 += k0;  x1 += k1;
  tf_round4(x0, x1, 13, 15, 26, 6);  x0 += k1;  x1 += ks2 + 1u;
  tf_round4(x0, x1, 17, 29, 16, 24); x0 += ks2; x1 += k0  + 2u;
  tf_round4(x0, x1, 13, 15, 26, 6);  x0 += k0;  x1 += k1  + 3u;
  tf_round4(x0, x1, 17, 29, 16, 24); x0 += k1;  x1 += ks2 + 4u;
  tf_round4(x0, x1, 13, 15, 26, 6);  x0 += ks2; x1 += k0  + 5u;
}

__device__ __forceinline__ float jax_gumbel(uint32_t flat_idx) {
  uint32_t x0 = 0u, x1 = flat_idx;
  threefry2x32(0u, 42u, x0, x1);
  uint32_t bits = x0 ^ x1;
  uint32_t fb = (bits >> 9) | 0x3f800000u;
  float f = __uint_as_float(fb) - 1.0f;          // [0,1)
  float u = fmaxf(f, 1.17549435e-38f);
  return -__logf(-__logf(u));
}

__device__ __forceinline__ void dot4(float& a, float4 u, float4 v) {
  a = fmaf(u.x, v.x, a); a = fmaf(u.y, v.y, a);
  a = fmaf(u.z, v.z, a); a = fmaf(u.w, v.w, a);
}

// ---------------- K1: split-K tiled GEMM -> per-chunk partials ----------------
// Wcat col c: c<18 -> Wopp[c/6][d][c%6]; c>=18 -> W[d][c-18]
template<int NCH>
__global__ __launch_bounds__(128) void k1_gemm(
    const float* __restrict__ x, const float* __restrict__ Wopp,
    const float* __restrict__ W, float* __restrict__ part,
    float* __restrict__ ws_ent) {
  constexpr int NLOOP = 4 / NCH;                  // 128-wide chunks per block
  const int tile = blockIdx.x / NCH;              // 0..127
  const int ch = blockIdx.x % NCH;
  const int rowbase = tile * TROWS;
  __shared__ float xs[TROWS * LDSPAD];
  __shared__ float wt[24 * LDSPAD];
  const int t = threadIdx.x;
  const int rowg = t >> 3, colg = t & 7;          // 16 x 8
  float acc[2][3] = {{0.f, 0.f, 0.f}, {0.f, 0.f, 0.f}};

  for (int l = 0; l < NLOOP; ++l) {
    const int dbase = (ch * NLOOP + l) * 128;
    if (l) __syncthreads();
    // stage x tile: TROWS x 128 floats, coalesced float4
    for (int f = t; f < TROWS * 32; f += 128) {
      int row = f >> 5, c4 = (f & 31) << 2;
      float4 v = *(const float4*)(x + (size_t)(rowbase + row) * DIM + dbase + c4);
      *(float4*)(xs + row * LDSPAD + c4) = v;
    }
    // stage W chunk transposed: wt[c][dd]
    for (int i = t; i < 3072; i += 128) {
      int c = i % 24, dd = i / 24;
      int d = dbase + dd;
      float v = (c < 18) ? Wopp[(c / 6) * (DIM * 6) + d * 6 + (c % 6)]
                         : W[d * 6 + (c - 18)];
      wt[c * LDSPAD + dd] = v;
    }
    __syncthreads();
    const float* xp = xs + (rowg * 2) * LDSPAD;
    const float* wp = wt + (colg * 3) * LDSPAD;
#pragma unroll 4
    for (int dd = 0; dd < 128; dd += 4) {
      float4 x0 = *(const float4*)(xp + dd);
      float4 x1 = *(const float4*)(xp + LDSPAD + dd);
      float4 w0 = *(const float4*)(wp + dd);
      float4 w1 = *(const float4*)(wp + LDSPAD + dd);
      float4 w2 = *(const float4*)(wp + 2 * LDSPAD + dd);
      dot4(acc[0][0], x0, w0); dot4(acc[0][1], x0, w1); dot4(acc[0][2], x0, w2);
      dot4(acc[1][0], x1, w0); dot4(acc[1][1], x1, w1); dot4(acc[1][2], x1, w2);
    }
  }
  const int r0 = rowbase + rowg * 2, c0 = colg * 3;
  float* p = part + (size_t)ch * ACC_STRIDE;
#pragma unroll
  for (int rr = 0; rr < 2; rr++)
#pragma unroll
    for (int cc = 0; cc < 3; cc++)
      p[(r0 + rr) * 24 + c0 + cc] = acc[rr][cc];
  if (blockIdx.x == 0 && t == 0) ws_ent[0] = 0.f;   // zero entropy accumulator for k2
}

// ---------------- K2: softmax -> dist (d_out) + entropy atomic ----------------
__global__ __launch_bounds__(256) void k2_softmax(
    const float* __restrict__ part, const float* __restrict__ bopp,
    float* __restrict__ dout, float* __restrict__ ws_ent, int nch) {
  int row = blockIdx.x * 256 + threadIdx.x;       // 12288 = 3*4096 rows
  int k = row >> 12, b = row & 4095;
  float l[NUM_ACT];
#pragma unroll
  for (int a = 0; a < NUM_ACT; a++) {
    float s = bopp[k * 6 + a];
    for (int ch = 0; ch < nch; ch++)
      s += part[ch * ACC_STRIDE + b * 24 + k * 6 + a];
    l[a] = s;
  }
  float m = l[0];
#pragma unroll
  for (int a = 1; a < NUM_ACT; a++) m = fmaxf(m, l[a]);
  float e[NUM_ACT], Z = 0.f;
#pragma unroll
  for (int a = 0; a < NUM_ACT; a++) { e[a] = expf(l[a] - m); Z += e[a]; }
  float logZ = logf(Z);
  float H = 0.f;
#pragma unroll
  for (int a = 0; a < NUM_ACT; a++) {
    float pa = e[a] / Z;
    dout[BATCH * NUM_ACT + row * NUM_ACT + a] = pa;
    H -= pa * ((l[a] - m) - logZ);
  }
#pragma unroll
  for (int off = 32; off > 0; off >>= 1) H += __shfl_down(H, off);
  if ((threadIdx.x & 63) == 0) atomicAdd(ws_ent, H);
}

// ---------------- K3: sample + p2 + agent softmax + output ----------------
__global__ __launch_bounds__(256) void k3_agent(
    const float* __restrict__ part, const float* __restrict__ bopp,
    const float* __restrict__ W, const float* __restrict__ bias,
    const float* __restrict__ ws_ent, float* __restrict__ dout, int nch) {
  int b = blockIdx.x;
  int t = threadIdx.x;
  __shared__ float s_logits[NUM_OPP][NUM_ACT];
  __shared__ float s_dist[NUM_OPP][NUM_ACT];
  __shared__ float s_xw[NUM_ACT];
  __shared__ float s_bias[NUM_ACT];
  __shared__ float s_W2[NUM_OPP * NUM_ACT][NUM_ACT];
  __shared__ int   s_act[NUM_OPP][NUM_SAMPLE];
  __shared__ float s_prob[NUM_OPP][NUM_SAMPLE];
  __shared__ float s_p1[NUM_SAMPLE];
  __shared__ float s_sum;
  __shared__ float s_wq[NUM_SAMPLE][NUM_ACT];
  __shared__ float s_o[8][NUM_ACT];

  if (t < 18) {
    int k = t / 6, a = t - k * 6;
    float s = bopp[t];
    for (int ch = 0; ch < nch; ch++)
      s += part[ch * ACC_STRIDE + b * 24 + t];    // c = k*6+a = t
    s_logits[k][a] = s;
    s_dist[k][a] = dout[BATCH * NUM_ACT + (k * BATCH + b) * NUM_ACT + a];
  }
  if (t < NUM_ACT) {
    float s = 0.f;
    for (int ch = 0; ch < nch; ch++)
      s += part[ch * ACC_STRIDE + b * 24 + 18 + t];
    s_xw[t] = s;
    s_bias[t] = bias[t];
  }
  if (t >= 32 && t < 32 + 108) {
    int i = t - 32;
    s_W2[i / 6][i % 6] = W[DIM * NUM_ACT + i];
  }
  __syncthreads();

  if (t < NUM_OPP * NUM_SAMPLE) {
    int k = t / NUM_SAMPLE, s = t - k * NUM_SAMPLE;
    uint32_t base = ((uint32_t)(k * NUM_SAMPLE + s) * BATCH + (uint32_t)b) * NUM_ACT;
    float best = -3.4e38f;
    int bestA = 0;
#pragma unroll
    for (int a = 0; a < NUM_ACT; a++) {
      float v = s_logits[k][a] + jax_gumbel(base + a);
      if (v > best) { best = v; bestA = a; }      // first max wins
    }
    s_act[k][s] = bestA;
    s_prob[k][s] = s_dist[k][bestA];
  }
  __syncthreads();

  if (t < NUM_SAMPLE) s_p1[t] = s_prob[0][t] * s_prob[1][t] * s_prob[2][t];
  __syncthreads();
  if (t < 64) {                                    // single-wave butterfly over 80
    float v = s_p1[t];
    if (t < 16) v += s_p1[64 + t];
#pragma unroll
    for (int off = 32; off > 0; off >>= 1) v += __shfl_down(v, off);
    if (t == 0) s_sum = v;
  }
  __syncthreads();

  if (t < NUM_SAMPLE) {
    float w = s_p1[t] / s_sum;
    int a0 = s_act[0][t], a1 = s_act[1][t], a2 = s_act[2][t];
    float la[NUM_ACT];
#pragma unroll
    for (int a = 0; a < NUM_ACT; a++)
      la[a] = s_xw[a] + s_W2[a0][a] + s_W2[6 + a1][a] + s_W2[12 + a2][a] + s_bias[a];
    float m = la[0];
#pragma unroll
    for (int a = 1; a < NUM_ACT; a++) m = fmaxf(m, la[a]);
    float e[NUM_ACT], Z = 0.f;
#pragma unroll
    for (int a = 0; a < NUM_ACT; a++) { e[a] = expf(la[a] - m); Z += e[a]; }
#pragma unroll
    for (int a = 0; a < NUM_ACT; a++) s_wq[t][a] = w * (e[a] / Z);
  }
  __syncthreads();

  if (t < 48) {                                    // 8 chunks x 6 cols partial sums
    int sc = t / 6, a = t - sc * 6;
    float sm = 0.f;
    for (int i = 0; i < 10; i++) sm += s_wq[sc * 10 + i][a];
    s_o[sc][a] = sm;
  }
  __syncthreads();
  if (t < NUM_ACT) {
    float sm = 0.f;
#pragma unroll
    for (int sc = 0; sc < 8; sc++) sm += s_o[sc][t];
    dout[b * NUM_ACT + t] = sm;
  }
  if (b == 0 && t == 255) {
    dout[BATCH * NUM_ACT + NUM_OPP * BATCH * NUM_ACT] = ws_ent[0] * (1.0f / 12288.0f);
  }
}

extern "C" void kernel_launch(void* const* d_in, const int* in_sizes, int n_in,
                              void* d_out, int out_size, void* d_ws, size_t ws_size,
                              hipStream_t stream) {
  const float* x    = (const float*)d_in[0];
  const float* Wopp = (const float*)d_in[1];
  const float* bopp = (const float*)d_in[2];
  const float* W    = (const float*)d_in[3];
  const float* bias = (const float*)d_in[4];
  float* out = (float*)d_out;
  float* part = (float*)d_ws;

  size_t need4 = ((size_t)4 * ACC_STRIDE + 1) * sizeof(float);
  int nch = (ws_size >= need4) ? 4 : 1;            // nch=1 path fits 393 KB (known good)
  float* ws_ent = part + (size_t)nch * ACC_STRIDE;

  if (nch == 4) k1_gemm<4><<<512, 128, 0, stream>>>(x, Wopp, W, part, ws_ent);
  else          k1_gemm<1><<<128, 128, 0, stream>>>(x, Wopp, W, part, ws_ent);
  k2_softmax<<<48, 256, 0, stream>>>(part, bopp, out, ws_ent, nch);
  k3_agent<<<4096, 256, 0, stream>>>(part, bopp, W, bias, ws_ent, out, nch);
}